// Round 1
// baseline (1197.953 us; speedup 1.0000x reference)
//
#include <hip/hip_runtime.h>
#include <hip/hip_bf16.h>
#include <cstdint>
#include <cstddef>

namespace {

constexpr int B_ = 32, F_ = 64, T_ = 20, N_ = 512, A_ = 64;
constexpr int EINC = 2048, NEDGE = 128, COUT = 128, CIN = 128;
constexpr int THREADS = 512;

// ---- LDS layout (word offsets) ----
constexpr int L_NID  = 0;                 // 2048 int
constexpr int L_EID  = L_NID + EINC;      // 2048 int
constexpr int L_SORT = L_EID + EINC;      // 2048 int (node-sorted edge ids)
constexpr int L_OFF  = L_SORT + EINC;     // 513 int (+pad)
constexpr int L_DEGE = L_OFF + 516;       // 128 int
constexpr int L_DEGN = L_DEGE + NEDGE;    // 512 int
constexpr int L_EQ   = 7304;              // 16384 f32, 16B aligned (Eq, later Xq)
constexpr int L_STG  = L_EQ + NEDGE*CIN;  // 8192 f32 (feat chunk / theta bf16)
constexpr int LDS_WORDS = L_STG + N_*16;  // 31880
constexpr int LDS_BYTES = LDS_WORDS * 4;  // 127520 B (< 160K HW max)

__device__ inline unsigned short f2bf(float f) {
    unsigned int u = __float_as_uint(f);
    u = u + 0x7FFFu + ((u >> 16) & 1u);   // RNE (inputs are finite normals)
    return (unsigned short)(u >> 16);
}
__device__ inline float bf2f(unsigned short h) {
    return __uint_as_float(((unsigned int)h) << 16);
}

__global__ __launch_bounds__(THREADS)
void hgconv(const float* __restrict__ x, const int* __restrict__ H,
            const float* __restrict__ ssa, const float* __restrict__ theta,
            const float* __restrict__ bias, float* __restrict__ out)
{
    extern __shared__ float sf[];
    int* si = (int*)sf;

    const int tid = (int)threadIdx.x;
    const int bt  = (int)blockIdx.x;       // b*T + t
    const int b   = bt / T_;
    const int t   = bt - b * T_;

    int* s_nid = si + L_NID;
    int* s_eid = si + L_EID;
    int* s_srt = si + L_SORT;
    int* s_off = si + L_OFF;
    int* s_dge = si + L_DEGE;
    int* s_dgn = si + L_DEGN;
    float* s_Eq = sf + L_EQ;
    float* s_st = sf + L_STG;
    unsigned short* s_th  = (unsigned short*)(sf + L_STG);
    unsigned int*   s_th32 = (unsigned int*)(sf + L_STG);

    // ---- chunk loader: 16 channels x 512 nodes into registers ----
    // chunks 0..3 = x channels (feat[n][ch] = x[b][ch][t][n], coalesced along n)
    // chunks 4..7 = ssa channels (one 64B line per node, float4 x4)
    auto load_chunk = [&](int c, float* vv) {
        if (c < 4) {
            #pragma unroll
            for (int j = 0; j < 16; ++j) {
                int ch = c * 16 + j;
                vv[j] = x[(((size_t)b * F_ + ch) * T_ + t) * N_ + tid];
            }
        } else {
            const float* sr = ssa + ((size_t)bt * N_ + tid) * A_ + (c - 4) * 16;
            float4 v0 = *(const float4*)(sr + 0);
            float4 v1 = *(const float4*)(sr + 4);
            float4 v2 = *(const float4*)(sr + 8);
            float4 v3 = *(const float4*)(sr + 12);
            vv[0]=v0.x; vv[1]=v0.y; vv[2]=v0.z; vv[3]=v0.w;
            vv[4]=v1.x; vv[5]=v1.y; vv[6]=v1.z; vv[7]=v1.w;
            vv[8]=v2.x; vv[9]=v2.y; vv[10]=v2.z; vv[11]=v2.w;
            vv[12]=v3.x; vv[13]=v3.y; vv[14]=v3.z; vv[15]=v3.w;
        }
    };

    // ---- P0: load incidence lists, zero counters/accumulators; prefetch chunk 0 ----
    float vv[16];
    load_chunk(0, vv);

    const int* Hb = H + (size_t)bt * (2 * EINC);
    #pragma unroll
    for (int k = 0; k < EINC / THREADS; ++k) {
        int i = tid + k * THREADS;
        s_nid[i] = Hb[i];
        s_eid[i] = Hb[EINC + i];
    }
    s_dgn[tid] = 0;
    if (tid < NEDGE) s_dge[tid] = 0;
    #pragma unroll
    for (int k = 0; k < (NEDGE * CIN) / THREADS; ++k)
        s_Eq[tid + k * THREADS] = 0.0f;
    __syncthreads();

    // ---- P1: degrees (with multiplicity, matches segment_sum of ones) ----
    #pragma unroll
    for (int k = 0; k < EINC / THREADS; ++k) {
        int i = tid + k * THREADS;
        atomicAdd(&s_dgn[s_nid[i]], 1);
        atomicAdd(&s_dge[s_eid[i]], 1);
    }
    __syncthreads();

    // ---- P2: per-chunk stage + scatter (node->edge accumulation, Hᵀ·feat) ----
    const int sg = tid >> 4;   // incidence subgroup 0..31
    const int sj = tid & 15;   // channel-in-chunk
    for (int c = 0; c < 8; ++c) {
        // write staged registers to LDS (swizzled: bank-conflict <= 2-way)
        #pragma unroll
        for (int j = 0; j < 16; ++j)
            s_st[tid * 16 + (j ^ ((tid >> 1) & 15))] = vv[j];
        __syncthreads();

        // prefetch next chunk's global data into registers (hides HBM under scatter)
        float nv[16];
        if (c < 7) load_chunk(c + 1, nv);

        const int cbase = c * 16;
        #pragma unroll 4
        for (int base = 0; base < EINC; base += 32) {
            int i  = base + sg;
            int nd = s_nid[i];
            int e  = s_eid[i];
            float v = s_st[nd * 16 + (sj ^ ((nd >> 1) & 15))];
            atomicAdd(&s_Eq[e * CIN + ((cbase + sj) ^ (e & 31))], v);
        }
        __syncthreads();

        if (c < 7) {
            #pragma unroll
            for (int j = 0; j < 16; ++j) vv[j] = nv[j];
        }
    }

    // ---- P3: B^-1 scale, stage theta as bf16, node prefix-sum, counting sort ----
    #pragma unroll
    for (int k = 0; k < (NEDGE * CIN) / THREADS; ++k) {
        int idx = tid + k * THREADS;
        int e = idx >> 7;                   // row-uniform: swizzle irrelevant
        int d = s_dge[e];
        float binv = (d > 0) ? (1.0f / (float)d) : 0.0f;
        s_Eq[idx] *= binv;
    }
    #pragma unroll
    for (int k = 0; k < (COUT * CIN / 2) / THREADS; ++k) {
        int w = tid + k * THREADS;          // packed word index (2 bf16 per word)
        const float2 tv = *(const float2*)(theta + 2 * (size_t)w);
        s_th32[w] = ((unsigned int)f2bf(tv.y) << 16) | (unsigned int)f2bf(tv.x);
    }
    if (tid < 64) {                          // wave0: exclusive scan of node degrees
        const int l = tid;
        int v, loc[8], run = 0;
        #pragma unroll
        for (int q = 0; q < 8; ++q) { v = s_dgn[l * 8 + q]; loc[q] = run; run += v; }
        int scan = run;
        #pragma unroll
        for (int d = 1; d < 64; d <<= 1) {
            int o = __shfl_up(scan, d);
            if (l >= d) scan += o;
        }
        int excl = scan - run;
        #pragma unroll
        for (int q = 0; q < 8; ++q) s_off[l * 8 + q] = excl + loc[q];
        if (l == 63) s_off[N_] = scan;       // = EINC
    }
    __syncthreads();
    s_dgn[tid] = s_off[tid];                 // reuse degn as insert cursor
    __syncthreads();
    #pragma unroll
    for (int k = 0; k < EINC / THREADS; ++k) {
        int i = tid + k * THREADS;
        int nd = s_nid[i];
        int pos = atomicAdd(&s_dgn[nd], 1);
        s_srt[pos] = s_eid[i];
    }
    __syncthreads();

    // ---- P4: Xq = (B^-1 Hᵀ feat) · Θᵀ   (fp32, register-tiled 4e x 8co) ----
    {
        const int et = tid & 31;
        const int ct = tid >> 5;             // 0..15
        float acc[4][8];
        #pragma unroll
        for (int i = 0; i < 4; ++i)
            #pragma unroll
            for (int j = 0; j < 8; ++j) acc[i][j] = 0.0f;

        for (int ci = 0; ci < CIN; ci += 2) {
            float a0[4], a1[4];
            #pragma unroll
            for (int i = 0; i < 4; ++i) {
                int e = et * 4 + i;
                // pair {ci, ci+1} is adjacent after XOR swizzle; order flips with e&1 (== i&1, static)
                float2 f2 = *(const float2*)&s_Eq[e * CIN + (ci ^ (e & 30))];
                if (i & 1) { a1[i] = f2.x; a0[i] = f2.y; }
                else       { a0[i] = f2.x; a1[i] = f2.y; }
            }
            #pragma unroll
            for (int j = 0; j < 8; ++j) {
                unsigned int p = s_th32[((ct * 8 + j) * CIN + ci) >> 1];
                float b0 = bf2f((unsigned short)(p & 0xFFFFu));
                float b1 = bf2f((unsigned short)(p >> 16));
                #pragma unroll
                for (int i = 0; i < 4; ++i) {
                    acc[i][j] = fmaf(a0[i], b0, acc[i][j]);
                    acc[i][j] = fmaf(a1[i], b1, acc[i][j]);
                }
            }
        }
        __syncthreads();                     // all Eq reads done before overwrite
        #pragma unroll
        for (int i = 0; i < 4; ++i) {
            int e = et * 4 + i;
            #pragma unroll
            for (int j = 0; j < 8; ++j) {
                int co = ct * 8 + j;
                s_Eq[e * CIN + (co ^ (e & 31))] = acc[i][j];   // now holds Xq
            }
        }
        __syncthreads();
    }

    // ---- P5: edge->node gather, D^-1 scale, bias, coalesced store ----
    {
        const int lw = tid & 31;
        const int g  = tid >> 5;             // 0..15
        float bsv[4];
        #pragma unroll
        for (int r = 0; r < 4; ++r) bsv[r] = bias[lw + 32 * r];
        for (int n = g; n < N_; n += 16) {
            int o0 = s_off[n], o1 = s_off[n + 1];
            float fa[4] = {0.f, 0.f, 0.f, 0.f};
            for (int k = o0; k < o1; ++k) {
                int e = s_srt[k];
                #pragma unroll
                for (int r = 0; r < 4; ++r)
                    fa[r] += s_Eq[e * CIN + ((lw + 32 * r) ^ (e & 31))];
            }
            float dinv = (o1 > o0) ? 1.0f / (float)(o1 - o0) : 0.0f;
            size_t ob = ((size_t)bt * N_ + n) * COUT;
            #pragma unroll
            for (int r = 0; r < 4; ++r)
                out[ob + lw + 32 * r] = fa[r] * dinv + bsv[r];
        }
    }
}

} // namespace

extern "C" void kernel_launch(void* const* d_in, const int* in_sizes, int n_in,
                              void* d_out, int out_size, void* d_ws, size_t ws_size,
                              hipStream_t stream) {
    const float* x     = (const float*)d_in[0];
    const int*   H     = (const int*)d_in[1];
    const float* ssa   = (const float*)d_in[2];
    // d_in[3] = W, unused by the conv (matches reference)
    const float* theta = (const float*)d_in[4];
    const float* bias  = (const float*)d_in[5];
    float* outp = (float*)d_out;

    // allow >64KB dynamic LDS (idempotent, host-side, graph-capture safe)
    (void)hipFuncSetAttribute((const void*)&hgconv,
                              hipFuncAttributeMaxDynamicSharedMemorySize, LDS_BYTES);

    hipLaunchKernelGGL(hgconv, dim3(B_ * T_), dim3(THREADS), LDS_BYTES, stream,
                       x, H, ssa, theta, bias, outp);
}

// Round 2
// 1179.180 us; speedup vs baseline: 1.0159x; 1.0159x over previous
//
#include <hip/hip_runtime.h>
#include <cstdint>
#include <cstddef>

namespace {

constexpr int B_ = 32, F_ = 64, T_ = 20, N_ = 512, A_ = 64;
constexpr int EINC = 2048, NEDGE = 128, COUT = 128, CIN = 128;
constexpr int THREADS = 1024;

// ---- LDS layout (word offsets) ----
constexpr int L_NID  = 0;                 // 2048 int
constexpr int L_EID  = L_NID + EINC;      // 2048 int
constexpr int L_SORT = L_EID + EINC;      // 2048 int (node-sorted edge ids)
constexpr int L_OFF  = L_SORT + EINC;     // 513 int (+pad)
constexpr int L_DEGE = L_OFF + 516;       // 128 int
constexpr int L_DEGN = L_DEGE + NEDGE;    // 512 int
constexpr int L_EQ   = 7304;              // 16384 f32 (Eq, later Xq), 16B aligned
constexpr int L_STG  = L_EQ + NEDGE*CIN;  // 8192 f32 (feat chunk / theta bf16)
constexpr int LDS_WORDS = L_STG + N_*16;  // 31880
constexpr int LDS_BYTES = LDS_WORDS * 4;  // 127520 B

typedef float f32x8 __attribute__((ext_vector_type(8)));

__device__ inline unsigned short f2bf(float f) {
    unsigned int u = __float_as_uint(f);
    u = u + 0x7FFFu + ((u >> 16) & 1u);   // RNE (inputs are finite normals)
    return (unsigned short)(u >> 16);
}
__device__ inline float bf2f(unsigned short h) {
    return __uint_as_float(((unsigned int)h) << 16);
}

// Inline chunk loader (macro: no function call, no array-pointer escape -> no scratch).
// chunk c<4: x channels (feat[n][ch] = x[b][ch][t][n], coalesced along n)
// chunk c>=4: ssa channels (float4 x2 per thread)
#define LOAD_CHUNK(CC, DST) do {                                              \
    const int c_ = (CC);                                                      \
    if (c_ < 4) {                                                             \
        const float* xr_ = x + (((size_t)b * F_ + (c_ * 16 + hf * 8)) * T_ + t) * N_ + n; \
        _Pragma("unroll")                                                     \
        for (int j_ = 0; j_ < 8; ++j_)                                        \
            DST[j_] = xr_[(size_t)j_ * T_ * N_];                              \
    } else {                                                                  \
        const float* sr_ = ssa + ((size_t)bt * N_ + n) * A_ + (c_ - 4) * 16 + hf * 8; \
        float4 u0_ = *(const float4*)(sr_);                                   \
        float4 u1_ = *(const float4*)(sr_ + 4);                               \
        DST[0] = u0_.x; DST[1] = u0_.y; DST[2] = u0_.z; DST[3] = u0_.w;       \
        DST[4] = u1_.x; DST[5] = u1_.y; DST[6] = u1_.z; DST[7] = u1_.w;       \
    }                                                                         \
} while (0)

__global__ __launch_bounds__(THREADS)
void hgconv(const float* __restrict__ x, const int* __restrict__ H,
            const float* __restrict__ ssa, const float* __restrict__ theta,
            const float* __restrict__ bias, float* __restrict__ out)
{
    extern __shared__ float sf[];
    int* si = (int*)sf;

    const int tid = (int)threadIdx.x;
    const int bt  = (int)blockIdx.x;       // b*T + t
    const int b   = bt / T_;
    const int t   = bt - b * T_;

    int* s_nid = si + L_NID;
    int* s_eid = si + L_EID;
    int* s_srt = si + L_SORT;
    int* s_off = si + L_OFF;
    int* s_dge = si + L_DEGE;
    int* s_dgn = si + L_DEGN;
    float* s_Eq = sf + L_EQ;
    float* s_st = sf + L_STG;
    unsigned int* s_th32 = (unsigned int*)(sf + L_STG);

    const int n  = tid & (N_ - 1);          // node this thread stages
    const int hf = tid >> 9;                // which 8-channel half of the chunk

    // ---- P0: load incidence lists, zero counters/accumulators ----
    const int* Hb = H + (size_t)bt * (2 * EINC);
    #pragma unroll
    for (int k = 0; k < EINC / THREADS; ++k) {
        int i = tid + k * THREADS;
        s_nid[i] = Hb[i];
        s_eid[i] = Hb[EINC + i];
    }
    if (tid < N_)    s_dgn[tid] = 0;
    if (tid < NEDGE) s_dge[tid] = 0;
    #pragma unroll
    for (int k = 0; k < (NEDGE * CIN) / THREADS; ++k)
        s_Eq[tid + k * THREADS] = 0.0f;
    __syncthreads();

    // ---- P1: degrees (with multiplicity, matches segment_sum of ones) ----
    #pragma unroll
    for (int k = 0; k < EINC / THREADS; ++k) {
        int i = tid + k * THREADS;
        atomicAdd(&s_dgn[s_nid[i]], 1);
        atomicAdd(&s_dge[s_eid[i]], 1);
    }
    __syncthreads();

    // Only stage feat for nodes that actually appear in the incidence list
    // (data-independent: deg==0 rows contribute nothing to Eq).
    const bool act = s_dgn[n] > 0;

    // ---- P2: per-chunk stage + scatter (node->edge accumulation, Hᵀ·feat) ----
    f32x8 vv;
    if (act) LOAD_CHUNK(0, vv);

    const int sg = tid >> 4;   // incidence subgroup 0..63
    const int sj = tid & 15;   // channel-in-chunk
    for (int c = 0; c < 8; ++c) {
        if (act) {
            #pragma unroll
            for (int j = 0; j < 8; ++j)
                s_st[n * 16 + ((hf * 8 + j) ^ ((n >> 1) & 15))] = vv[j];
        }
        __syncthreads();

        f32x8 nv;
        if (c < 7 && act) LOAD_CHUNK(c + 1, nv);   // prefetch hides HBM under scatter

        const int cbase = c * 16;
        #pragma unroll 4
        for (int base = 0; base < EINC; base += 64) {
            int i  = base + sg;
            int nd = s_nid[i];
            int e  = s_eid[i];
            float v = s_st[nd * 16 + (sj ^ ((nd >> 1) & 15))];
            atomicAdd(&s_Eq[e * CIN + ((cbase + sj) ^ (e & 31))], v);
        }
        __syncthreads();

        if (c < 7 && act) vv = nv;
    }

    // ---- P3: B^-1 scale, stage theta as bf16 (swizzled), prefix-sum, counting sort ----
    #pragma unroll
    for (int k = 0; k < (NEDGE * CIN) / THREADS; ++k) {
        int idx = tid + k * THREADS;
        int e = idx >> 7;                   // row-uniform: swizzle irrelevant
        int d = s_dge[e];
        float binv = (d > 0) ? (1.0f / (float)d) : 0.0f;
        s_Eq[idx] *= binv;
    }
    #pragma unroll
    for (int k = 0; k < (COUT * CIN / 2) / THREADS; ++k) {
        int w = tid + k * THREADS;          // packed word index (2 bf16 per word)
        const float2 tv = *(const float2*)(theta + 2 * (size_t)w);
        // swizzle so P4's 16-way co-strided read spreads across banks
        s_th32[w ^ ((w >> 6) & 31)] =
            ((unsigned int)f2bf(tv.y) << 16) | (unsigned int)f2bf(tv.x);
    }
    if (tid < 64) {                          // wave0: exclusive scan of node degrees
        const int l = tid;
        int v, loc[8], run = 0;
        #pragma unroll
        for (int q = 0; q < 8; ++q) { v = s_dgn[l * 8 + q]; loc[q] = run; run += v; }
        int scan = run;
        #pragma unroll
        for (int d = 1; d < 64; d <<= 1) {
            int o = __shfl_up(scan, d);
            if (l >= d) scan += o;
        }
        int excl = scan - run;
        #pragma unroll
        for (int q = 0; q < 8; ++q) s_off[l * 8 + q] = excl + loc[q];
        if (l == 63) s_off[N_] = scan;       // = EINC
    }
    __syncthreads();
    if (tid < N_) s_dgn[tid] = s_off[tid];   // reuse degn as insert cursor
    __syncthreads();
    #pragma unroll
    for (int k = 0; k < EINC / THREADS; ++k) {
        int i = tid + k * THREADS;
        int nd = s_nid[i];
        int pos = atomicAdd(&s_dgn[nd], 1);
        s_srt[pos] = s_eid[i];
    }
    __syncthreads();

    // ---- P4: Xq = (B^-1 Hᵀ feat) · Θᵀ   (fp32 FMA, 2 edges x 8 couts per thread) ----
    {
        const int et = tid & 63;
        const int ct = tid >> 6;             // 0..15
        const int e0 = et * 2, e1 = e0 + 1;
        const int esw = e0 & 30;             // same for e1
        f32x8 acc0 = {0,0,0,0,0,0,0,0};
        f32x8 acc1 = {0,0,0,0,0,0,0,0};

        for (int ci = 0; ci < CIN; ci += 2) {
            float2 p0 = *(const float2*)&s_Eq[e0 * CIN + (ci ^ esw)];
            float2 p1 = *(const float2*)&s_Eq[e1 * CIN + (ci ^ esw)];
            // e1 odd: its swizzle flips the pair order
            float a00 = p0.x, a01 = p0.y;    // e0: channels ci, ci+1
            float a10 = p1.y, a11 = p1.x;    // e1: channels ci, ci+1
            #pragma unroll
            for (int j = 0; j < 8; ++j) {
                int w = (ct * 8 + j) * 64 + (ci >> 1);
                unsigned int pk = s_th32[w ^ ((w >> 6) & 31)];
                float tb0 = bf2f((unsigned short)(pk & 0xFFFFu));
                float tb1 = bf2f((unsigned short)(pk >> 16));
                acc0[j] = fmaf(a00, tb0, acc0[j]);
                acc0[j] = fmaf(a01, tb1, acc0[j]);
                acc1[j] = fmaf(a10, tb0, acc1[j]);
                acc1[j] = fmaf(a11, tb1, acc1[j]);
            }
        }
        __syncthreads();                     // all Eq reads done before overwrite
        #pragma unroll
        for (int j = 0; j < 8; ++j) {
            int co = ct * 8 + j;
            s_Eq[e0 * CIN + (co ^ (e0 & 31))] = acc0[j];   // now holds Xq
            s_Eq[e1 * CIN + (co ^ (e1 & 31))] = acc1[j];
        }
        __syncthreads();
    }

    // ---- P5: edge->node gather, D^-1 scale, bias, coalesced store ----
    {
        const int lw = tid & 31;
        const int g  = tid >> 5;             // 0..31
        float bs0 = bias[lw], bs1 = bias[lw + 32], bs2 = bias[lw + 64], bs3 = bias[lw + 96];
        for (int nn = g; nn < N_; nn += 32) {
            int o0 = s_off[nn], o1 = s_off[nn + 1];
            float f0 = 0.f, f1 = 0.f, f2 = 0.f, f3 = 0.f;
            for (int k = o0; k < o1; ++k) {
                int e = s_srt[k];
                int base = e * CIN, sw = e & 31;
                f0 += s_Eq[base + ((lw      ) ^ sw)];
                f1 += s_Eq[base + ((lw + 32) ^ sw)];
                f2 += s_Eq[base + ((lw + 64) ^ sw)];
                f3 += s_Eq[base + ((lw + 96) ^ sw)];
            }
            float dinv = (o1 > o0) ? 1.0f / (float)(o1 - o0) : 0.0f;
            size_t ob = ((size_t)bt * N_ + nn) * COUT;
            out[ob + lw     ] = f0 * dinv + bs0;
            out[ob + lw + 32] = f1 * dinv + bs1;
            out[ob + lw + 64] = f2 * dinv + bs2;
            out[ob + lw + 96] = f3 * dinv + bs3;
        }
    }
}

} // namespace

extern "C" void kernel_launch(void* const* d_in, const int* in_sizes, int n_in,
                              void* d_out, int out_size, void* d_ws, size_t ws_size,
                              hipStream_t stream) {
    const float* x     = (const float*)d_in[0];
    const int*   H     = (const int*)d_in[1];
    const float* ssa   = (const float*)d_in[2];
    // d_in[3] = W, unused by the conv (matches reference)
    const float* theta = (const float*)d_in[4];
    const float* bias  = (const float*)d_in[5];
    float* outp = (float*)d_out;

    (void)hipFuncSetAttribute((const void*)&hgconv,
                              hipFuncAttributeMaxDynamicSharedMemorySize, LDS_BYTES);

    hipLaunchKernelGGL(hgconv, dim3(B_ * T_), dim3(THREADS), LDS_BYTES, stream,
                       x, H, ssa, theta, bias, outp);
}

// Round 4
// 164.924 us; speedup vs baseline: 7.2637x; 7.1499x over previous
//
#include <hip/hip_runtime.h>
#include <cstdint>
#include <cstddef>

namespace {

constexpr int B_ = 32, F_ = 64, T_ = 20, N_ = 512, A_ = 64;
constexpr int EINC = 2048, NEDGE = 128, COUT = 128, CIN = 128;
constexpr int THREADS = 1024;

// ---- LDS layout (word offsets) ----
// Theta (8192 packed-bf16 words) is SPLIT: words [0,4096) overlay s_nid/s_eid
// (dead after P3); words [4096,8192) live at L_TH. Split boundary = co 64,
// and each P5 thread's co-rows sit entirely in one half (base is per-thread uniform).
constexpr int L_NID  = 0;        // 2048 int  node ids          (-> theta A after P3)
constexpr int L_EID  = 2048;     // 2048 int  edge ids          (-> theta A after P3)
constexpr int L_SRT  = 4096;     // 2048 int  edge ids sorted by node
constexpr int L_ESRT = 6144;     // 2048 int  node ids sorted by edge
constexpr int L_OFFN = 8192;     // 513 int (+pad 3)
constexpr int L_OFFE = 8708;     // 129 int (+pad 3)
constexpr int L_DEGN = 8840;     // 512 int
constexpr int L_DEGE = 9352;     // 128 int
constexpr int L_CURN = 9480;     // 512 int
constexpr int L_CURE = 9992;     // 128 int
constexpr int L_TH   = 10120;    // 4096 u32: theta words [4096,8192)
constexpr int L_EQ   = 14216;    // 16384 f32 Eq -> Xq (swizzled rows)
constexpr int L_ST   = 30600;    // 512*17 f32 feat chunk (stride-17 pad)
constexpr int LDS_WORDS = L_ST + N_ * 17;   // 39304
constexpr int LDS_BYTES = LDS_WORDS * 4;    // 157216 (<160K)

typedef float f32x8 __attribute__((ext_vector_type(8)));

__device__ inline unsigned short f2bf(float f) {
    unsigned int u = __float_as_uint(f);
    u = u + 0x7FFFu + ((u >> 16) & 1u);   // RNE
    return (unsigned short)(u >> 16);
}
__device__ inline float bf2f(unsigned short h) {
    return __uint_as_float(((unsigned int)h) << 16);
}

// chunk c<4: x channels (feat[n][ch] = x[b][ch][t][n], coalesced along n)
// chunk c>=4: ssa channels (float4 x2 per thread)
#define LOAD_CHUNK(CC, DST) do {                                              \
    const int c_ = (CC);                                                      \
    if (c_ < 4) {                                                             \
        const float* xr_ = x + (((size_t)b * F_ + (c_ * 16 + hf * 8)) * T_ + t) * N_ + n; \
        _Pragma("unroll")                                                     \
        for (int j_ = 0; j_ < 8; ++j_)                                        \
            DST[j_] = xr_[(size_t)j_ * T_ * N_];                              \
    } else {                                                                  \
        const float* sr_ = ssa + ((size_t)bt * N_ + n) * A_ + (c_ - 4) * 16 + hf * 8; \
        float4 u0_ = *(const float4*)(sr_);                                   \
        float4 u1_ = *(const float4*)(sr_ + 4);                               \
        DST[0] = u0_.x; DST[1] = u0_.y; DST[2] = u0_.z; DST[3] = u0_.w;       \
        DST[4] = u1_.x; DST[5] = u1_.y; DST[6] = u1_.z; DST[7] = u1_.w;       \
    }                                                                         \
} while (0)

__global__ __launch_bounds__(THREADS)
void hgconv(const float* __restrict__ x, const int* __restrict__ H,
            const float* __restrict__ ssa, const float* __restrict__ theta,
            const float* __restrict__ bias, float* __restrict__ out)
{
    extern __shared__ float sf[];
    int* si = (int*)sf;

    const int tid = (int)threadIdx.x;
    const int bt  = (int)blockIdx.x;
    const int b   = bt / T_;
    const int t   = bt - b * T_;

    int* s_nid = si + L_NID;
    int* s_eid = si + L_EID;
    int* s_srt = si + L_SRT;
    int* s_esr = si + L_ESRT;
    int* s_ofn = si + L_OFFN;
    int* s_ofe = si + L_OFFE;
    int* s_dgn = si + L_DEGN;
    int* s_dge = si + L_DEGE;
    int* s_cun = si + L_CURN;
    int* s_cue = si + L_CURE;
    float* s_Eq = sf + L_EQ;
    float* s_st = sf + L_ST;

    const int n  = tid & (N_ - 1);
    const int hf = tid >> 9;

    // ---- P0: load incidence, zero degrees ----
    const int* Hb = H + (size_t)bt * (2 * EINC);
    #pragma unroll
    for (int k = 0; k < EINC / THREADS; ++k) {
        int i = tid + k * THREADS;
        s_nid[i] = Hb[i];
        s_eid[i] = Hb[EINC + i];
    }
    if (tid < N_)    s_dgn[tid] = 0;
    if (tid < NEDGE) s_dge[tid] = 0;
    __syncthreads();

    // ---- P1: degrees (int atomics, 4 per thread) ----
    #pragma unroll
    for (int k = 0; k < EINC / THREADS; ++k) {
        int i = tid + k * THREADS;
        atomicAdd(&s_dgn[s_nid[i]], 1);
        atomicAdd(&s_dge[s_eid[i]], 1);
    }
    __syncthreads();

    // active-node predicate; issue chunk-0 load now (latency hides under sort)
    const bool act = s_dgn[n] > 0;
    f32x8 vv;
    if (act) LOAD_CHUNK(0, vv);

    // ---- P2: exclusive scans (wave0: edges, wave1: nodes) ----
    if (tid < 64) {                      // edge offsets: 2 per lane
        const int l = tid;
        int d0 = s_dge[2 * l], d1 = s_dge[2 * l + 1];
        int run = d0 + d1;
        int scan = run;
        #pragma unroll
        for (int d = 1; d < 64; d <<= 1) {
            int o = __shfl_up(scan, d);
            if (l >= d) scan += o;
        }
        int excl = scan - run;
        s_ofe[2 * l] = excl;
        s_ofe[2 * l + 1] = excl + d0;
        if (l == 63) s_ofe[NEDGE] = scan;
    } else if (tid < 128) {              // node offsets: 8 per lane
        const int l = tid & 63;
        int v, loc[8], run = 0;
        #pragma unroll
        for (int q = 0; q < 8; ++q) { v = s_dgn[l * 8 + q]; loc[q] = run; run += v; }
        int scan = run;
        #pragma unroll
        for (int d = 1; d < 64; d <<= 1) {
            int o = __shfl_up(scan, d);
            if (l >= d) scan += o;
        }
        int excl = scan - run;
        #pragma unroll
        for (int q = 0; q < 8; ++q) s_ofn[l * 8 + q] = excl + loc[q];
        if (l == 63) s_ofn[N_] = scan;
    }
    __syncthreads();

    if (tid < N_)    s_cun[tid] = s_ofn[tid];
    if (tid < NEDGE) s_cue[tid] = s_ofe[tid];
    __syncthreads();

    // ---- P3: counting-sort scatter, both keys (int cursor atomics) ----
    #pragma unroll
    for (int k = 0; k < EINC / THREADS; ++k) {
        int i = tid + k * THREADS;
        int nd = s_nid[i];
        int e  = s_eid[i];
        int pe = atomicAdd(&s_cue[e], 1);
        s_esr[pe] = nd;
        int pn = atomicAdd(&s_cun[nd], 1);
        s_srt[pn] = e;
    }
    __syncthreads();                     // P3 done; s_nid/s_eid are now DEAD

    // ---- P3b: stage theta (bf16 packed) into split regions A=[0,4096) B=L_TH ----
    #pragma unroll
    for (int k = 0; k < (COUT * CIN / 2) / THREADS; ++k) {   // 8 iters
        int w = tid + k * THREADS;                            // 0..8191
        const float2 tv = *(const float2*)(theta + 2 * (size_t)w);
        unsigned int pk = ((unsigned int)f2bf(tv.y) << 16) | (unsigned int)f2bf(tv.x);
        // k<4 -> w<4096 -> region A (word w); k>=4 -> region B (word L_TH + w - 4096)
        ((unsigned int*)si)[(k < 4) ? w : (w + (L_TH - 4096))] = pk;
    }
    // (theta writes made visible to P5 by the chunk loop's barriers)

    // ---- P4: per-chunk stage + edge-side GATHER (no f32 atomics) ----
    const int eg = tid >> 3;             // edge 0..127
    const int ep = tid & 7;              // channel pair 0..7
    const int c0 = ep * 2, c1 = c0 + 1;
    for (int c = 0; c < 8; ++c) {
        if (act) {
            #pragma unroll
            for (int j = 0; j < 8; ++j)
                s_st[n * 17 + hf * 8 + j] = vv[j];
        }
        __syncthreads();                 // stage (+ theta at c==0) visible

        f32x8 nv;
        if (c < 7 && act) LOAD_CHUNK(c + 1, nv);   // prefetch under gather

        {
            int k0 = s_ofe[eg], k1 = s_ofe[eg + 1];
            float a0 = 0.f, a1 = 0.f;
            int k = k0;
            for (; k + 1 < k1; k += 2) {
                int ndA = s_esr[k], ndB = s_esr[k + 1];
                float vA0 = s_st[ndA * 17 + c0], vA1 = s_st[ndA * 17 + c1];
                float vB0 = s_st[ndB * 17 + c0], vB1 = s_st[ndB * 17 + c1];
                a0 += vA0 + vB0;
                a1 += vA1 + vB1;
            }
            if (k < k1) {
                int nd = s_esr[k];
                a0 += s_st[nd * 17 + c0];
                a1 += s_st[nd * 17 + c1];
            }
            float binv = (k1 > k0) ? 1.0f / (float)(k1 - k0) : 0.0f;
            const int cb = c * 16;
            s_Eq[eg * CIN + ((cb + c0) ^ (eg & 31))] = a0 * binv;
            s_Eq[eg * CIN + ((cb + c1) ^ (eg & 31))] = a1 * binv;
        }
        __syncthreads();

        if (c < 7 && act) vv = nv;
    }

    // ---- P5: Xq = Eq · Θᵀ   (fp32 FMA, 2 edges x 8 couts per thread) ----
    {
        const int et = tid & 63;
        const int ct = tid >> 6;             // 0..15
        const int e0 = et * 2, e1 = e0 + 1;
        const int esw = e0 & 30;
        // per-thread-uniform theta base: co = ct*8+j; co<64 <=> ct<8
        const unsigned int* thp =
            (const unsigned int*)si + ((ct < 8) ? 0 : L_TH);
        const int cth = (ct & 7) * 8;        // local co base within the half
        f32x8 acc0 = {0,0,0,0,0,0,0,0};
        f32x8 acc1 = {0,0,0,0,0,0,0,0};

        for (int ci = 0; ci < CIN; ci += 2) {
            float2 p0 = *(const float2*)&s_Eq[e0 * CIN + (ci ^ esw)];
            float2 p1 = *(const float2*)&s_Eq[e1 * CIN + (ci ^ esw)];
            float a00 = p0.x, a01 = p0.y;    // e0: ci, ci+1
            float a10 = p1.y, a11 = p1.x;    // e1: ci, ci+1 (bit0-flipped row)
            #pragma unroll
            for (int j = 0; j < 8; ++j) {
                unsigned int pk = thp[(cth + j) * 64 + (ci >> 1)];
                float tb0 = bf2f((unsigned short)(pk & 0xFFFFu));
                float tb1 = bf2f((unsigned short)(pk >> 16));
                acc0[j] = fmaf(a00, tb0, acc0[j]);
                acc0[j] = fmaf(a01, tb1, acc0[j]);
                acc1[j] = fmaf(a10, tb0, acc1[j]);
                acc1[j] = fmaf(a11, tb1, acc1[j]);
            }
        }
        __syncthreads();                     // all Eq reads done before overwrite
        #pragma unroll
        for (int j = 0; j < 8; ++j) {
            int co = ct * 8 + j;
            s_Eq[e0 * CIN + (co ^ (e0 & 31))] = acc0[j];   // now holds Xq
            s_Eq[e1 * CIN + (co ^ (e1 & 31))] = acc1[j];
        }
        __syncthreads();
    }

    // ---- P6: edge->node gather, D^-1 scale, bias, coalesced store ----
    {
        const int lw = tid & 31;
        const int g  = tid >> 5;             // 0..31
        float bs0 = bias[lw], bs1 = bias[lw + 32], bs2 = bias[lw + 64], bs3 = bias[lw + 96];
        for (int nn = g; nn < N_; nn += 32) {
            int o0 = s_ofn[nn], o1 = s_ofn[nn + 1];
            float f0 = 0.f, f1 = 0.f, f2 = 0.f, f3 = 0.f;
            for (int k = o0; k < o1; ++k) {
                int e = s_srt[k];
                int base = e * CIN, sw = e & 31;
                f0 += s_Eq[base + ((lw      ) ^ sw)];
                f1 += s_Eq[base + ((lw + 32) ^ sw)];
                f2 += s_Eq[base + ((lw + 64) ^ sw)];
                f3 += s_Eq[base + ((lw + 96) ^ sw)];
            }
            float dinv = (o1 > o0) ? 1.0f / (float)(o1 - o0) : 0.0f;
            size_t ob = ((size_t)bt * N_ + nn) * COUT;
            out[ob + lw     ] = f0 * dinv + bs0;
            out[ob + lw + 32] = f1 * dinv + bs1;
            out[ob + lw + 64] = f2 * dinv + bs2;
            out[ob + lw + 96] = f3 * dinv + bs3;
        }
    }
}

} // namespace

extern "C" void kernel_launch(void* const* d_in, const int* in_sizes, int n_in,
                              void* d_out, int out_size, void* d_ws, size_t ws_size,
                              hipStream_t stream) {
    const float* x     = (const float*)d_in[0];
    const int*   H     = (const int*)d_in[1];
    const float* ssa   = (const float*)d_in[2];
    // d_in[3] = W, unused by the conv (matches reference)
    const float* theta = (const float*)d_in[4];
    const float* bias  = (const float*)d_in[5];
    float* outp = (float*)d_out;

    (void)hipFuncSetAttribute((const void*)&hgconv,
                              hipFuncAttributeMaxDynamicSharedMemorySize, LDS_BYTES);

    hipLaunchKernelGGL(hgconv, dim3(B_ * T_), dim3(THREADS), LDS_BYTES, stream,
                       x, H, ssa, theta, bias, outp);
}

// Round 5
// 107.662 us; speedup vs baseline: 11.1269x; 1.5319x over previous
//
#include <hip/hip_runtime.h>
#include <cstdint>
#include <cstddef>

namespace {

constexpr int B_ = 32, F_ = 64, T_ = 20, N_ = 512, A_ = 64;
constexpr int EINC = 2048, NEDGE = 128, COUT = 128, CIN = 128;
constexpr int THREADS = 1024;

// ---- LDS layout (word offsets) ----
// Theta (8192 packed-bf16 words, XOR-swizzled) SPLIT: words [0,4096) overlay
// s_nid/s_eid (dead after P3); words [4096,8192) at L_TH. Split = co 64;
// MFMA waves have wave-uniform co-half -> base pointer per-wave uniform.
// Union region U: Eq16 (8192 u32, bf16-pairs, swizzled) + s_st (8704 f32)
// overlaid later by Xq f32 (128 rows x stride 132 = 16896 words).
constexpr int L_NID  = 0;        // 2048 int (-> theta A after P3)
constexpr int L_EID  = 2048;     // 2048 int (-> theta A after P3)
constexpr int L_SRT  = 4096;     // 2048 int  edge ids sorted by node
constexpr int L_ESRT = 6144;     // 2048 int  node ids sorted by edge
constexpr int L_OFFN = 8192;     // 513 int (+pad 3)
constexpr int L_OFFE = 8708;     // 129 int (+pad 3)
constexpr int L_DEGN = 8840;     // 512 int
constexpr int L_DEGE = 9352;     // 128 int
constexpr int L_CURN = 9480;     // 512 int
constexpr int L_CURE = 9992;     // 128 int
constexpr int L_TH   = 10120;    // 4096 u32: theta words [4096,8192)  (16B-aligned: 10120%4==0)
constexpr int L_U    = 14216;    // union region (16B-aligned: 14216%4==0)
constexpr int L_ST_OFF = 8192;   // s_st at L_U + 8192 (f32, 512*17)
constexpr int XQ_STRIDE = 132;   // padded Xq row stride (128+4): conflict-free rows
constexpr int LDS_WORDS = L_U + NEDGE * XQ_STRIDE;  // 14216+16896 = 31112
constexpr int LDS_BYTES = LDS_WORDS * 4;            // 124448 B

typedef float f32x8 __attribute__((ext_vector_type(8)));
typedef float f32x4v __attribute__((ext_vector_type(4)));
typedef short bf16x8v __attribute__((ext_vector_type(8)));   // 8 bf16 = 4 VGPRs

__device__ inline unsigned short f2bf(float f) {
    unsigned int u = __float_as_uint(f);
    u = u + 0x7FFFu + ((u >> 16) & 1u);   // RNE
    return (unsigned short)(u >> 16);
}

// chunk c<4: x channels (feat[n][ch] = x[b][ch][t][n], coalesced along n)
// chunk c>=4: ssa channels (float4 x2 per thread)
#define LOAD_CHUNK(CC, DST) do {                                              \
    const int c_ = (CC);                                                      \
    if (c_ < 4) {                                                             \
        const float* xr_ = x + (((size_t)b * F_ + (c_ * 16 + hf * 8)) * T_ + t) * N_ + n; \
        _Pragma("unroll")                                                     \
        for (int j_ = 0; j_ < 8; ++j_)                                        \
            DST[j_] = xr_[(size_t)j_ * T_ * N_];                              \
    } else {                                                                  \
        const float* sr_ = ssa + ((size_t)bt * N_ + n) * A_ + (c_ - 4) * 16 + hf * 8; \
        float4 u0_ = *(const float4*)(sr_);                                   \
        float4 u1_ = *(const float4*)(sr_ + 4);                               \
        DST[0] = u0_.x; DST[1] = u0_.y; DST[2] = u0_.z; DST[3] = u0_.w;       \
        DST[4] = u1_.x; DST[5] = u1_.y; DST[6] = u1_.z; DST[7] = u1_.w;       \
    }                                                                         \
} while (0)

__global__ __launch_bounds__(THREADS)
void hgconv(const float* __restrict__ x, const int* __restrict__ H,
            const float* __restrict__ ssa, const float* __restrict__ theta,
            const float* __restrict__ bias, float* __restrict__ out)
{
    extern __shared__ float sf[];
    int* si = (int*)sf;

    const int tid = (int)threadIdx.x;
    const int bt  = (int)blockIdx.x;
    const int b   = bt / T_;
    const int t   = bt - b * T_;

    int* s_nid = si + L_NID;
    int* s_eid = si + L_EID;
    int* s_srt = si + L_SRT;
    int* s_esr = si + L_ESRT;
    int* s_ofn = si + L_OFFN;
    int* s_ofe = si + L_OFFE;
    int* s_dgn = si + L_DEGN;
    int* s_dge = si + L_DEGE;
    int* s_cun = si + L_CURN;
    int* s_cue = si + L_CURE;
    unsigned int* s_eq16 = (unsigned int*)sf + L_U;       // bf16-pair Eq, swizzled
    float* s_st = sf + L_U + L_ST_OFF;                    // feat chunk, stride-17
    float* s_xq = sf + L_U;                               // Xq f32 (overlays Eq16+s_st)

    const int n  = tid & (N_ - 1);
    const int hf = tid >> 9;

    // ---- P0: load incidence, zero degrees ----
    const int* Hb = H + (size_t)bt * (2 * EINC);
    #pragma unroll
    for (int k = 0; k < EINC / THREADS; ++k) {
        int i = tid + k * THREADS;
        s_nid[i] = Hb[i];
        s_eid[i] = Hb[EINC + i];
    }
    if (tid < N_)    s_dgn[tid] = 0;
    if (tid < NEDGE) s_dge[tid] = 0;
    __syncthreads();

    // ---- P1: degrees (int atomics) ----
    #pragma unroll
    for (int k = 0; k < EINC / THREADS; ++k) {
        int i = tid + k * THREADS;
        atomicAdd(&s_dgn[s_nid[i]], 1);
        atomicAdd(&s_dge[s_eid[i]], 1);
    }
    __syncthreads();

    // active-node predicate; issue chunk-0 load now (latency hides under sort)
    const bool act = s_dgn[n] > 0;
    f32x8 vv;
    if (act) LOAD_CHUNK(0, vv);

    // ---- P2: exclusive scans (wave0: edges, wave1: nodes) ----
    if (tid < 64) {
        const int l = tid;
        int d0 = s_dge[2 * l], d1 = s_dge[2 * l + 1];
        int run = d0 + d1;
        int scan = run;
        #pragma unroll
        for (int d = 1; d < 64; d <<= 1) {
            int o = __shfl_up(scan, d);
            if (l >= d) scan += o;
        }
        int excl = scan - run;
        s_ofe[2 * l] = excl;
        s_ofe[2 * l + 1] = excl + d0;
        if (l == 63) s_ofe[NEDGE] = scan;
    } else if (tid < 128) {
        const int l = tid & 63;
        int v, loc[8], run = 0;
        #pragma unroll
        for (int q = 0; q < 8; ++q) { v = s_dgn[l * 8 + q]; loc[q] = run; run += v; }
        int scan = run;
        #pragma unroll
        for (int d = 1; d < 64; d <<= 1) {
            int o = __shfl_up(scan, d);
            if (l >= d) scan += o;
        }
        int excl = scan - run;
        #pragma unroll
        for (int q = 0; q < 8; ++q) s_ofn[l * 8 + q] = excl + loc[q];
        if (l == 63) s_ofn[N_] = scan;
    }
    __syncthreads();

    if (tid < N_)    s_cun[tid] = s_ofn[tid];
    if (tid < NEDGE) s_cue[tid] = s_ofe[tid];
    __syncthreads();

    // ---- P3: counting-sort scatter, both keys ----
    #pragma unroll
    for (int k = 0; k < EINC / THREADS; ++k) {
        int i = tid + k * THREADS;
        int nd = s_nid[i];
        int e  = s_eid[i];
        int pe = atomicAdd(&s_cue[e], 1);
        s_esr[pe] = nd;
        int pn = atomicAdd(&s_cun[nd], 1);
        s_srt[pn] = e;
    }
    __syncthreads();                     // s_nid/s_eid now DEAD

    // ---- P3b: stage theta bf16-packed, XOR-swizzled, split A/B regions ----
    // full-theta word w = co*64 + p (p = ci/2); stored at (w&~63)|(p ^ ((co&7)<<2))
    #pragma unroll
    for (int k = 0; k < (COUT * CIN / 2) / THREADS; ++k) {   // 8 iters
        int w  = tid + k * THREADS;                           // 0..8191
        int co = w >> 6, p = w & 63;
        const float2 tv = *(const float2*)(theta + 2 * (size_t)w);
        unsigned int pk = ((unsigned int)f2bf(tv.y) << 16) | (unsigned int)f2bf(tv.x);
        int wsw = (w & ~63) | (p ^ ((co & 7) << 2));
        ((unsigned int*)si)[(k < 4) ? wsw : (wsw + (L_TH - 4096))] = pk;
    }
    // (visible to P5 via the chunk loop's barriers)

    // ---- P4: per-chunk stage + edge-side gather -> Eq16 (packed bf16, swizzled) ----
    const int eg = tid >> 3;             // edge 0..127
    const int ep = tid & 7;              // channel pair 0..7
    const int c0 = ep * 2, c1 = c0 + 1;
    for (int c = 0; c < 8; ++c) {
        if (act) {
            #pragma unroll
            for (int j = 0; j < 8; ++j)
                s_st[n * 17 + hf * 8 + j] = vv[j];
        }
        __syncthreads();                 // stage (+ theta at c==0) visible

        f32x8 nv;
        if (c < 7 && act) LOAD_CHUNK(c + 1, nv);   // prefetch under gather

        {
            int k0 = s_ofe[eg], k1 = s_ofe[eg + 1];
            float a0 = 0.f, a1 = 0.f;
            int k = k0;
            for (; k + 1 < k1; k += 2) {
                int ndA = s_esr[k], ndB = s_esr[k + 1];
                a0 += s_st[ndA * 17 + c0] + s_st[ndB * 17 + c0];
                a1 += s_st[ndA * 17 + c1] + s_st[ndB * 17 + c1];
            }
            if (k < k1) {
                int nd = s_esr[k];
                a0 += s_st[nd * 17 + c0];
                a1 += s_st[nd * 17 + c1];
            }
            float binv = (k1 > k0) ? 1.0f / (float)(k1 - k0) : 0.0f;
            unsigned int pk = ((unsigned int)f2bf(a1 * binv) << 16)
                            |  (unsigned int)f2bf(a0 * binv);
            int p = c * 8 + ep;                       // word-in-row 0..63
            s_eq16[eg * 64 + (p ^ ((eg & 7) << 2))] = pk;
        }
        __syncthreads();

        if (c < 7 && act) vv = nv;
    }

    // ---- P5: Xq = Eq16 · Theta^T via MFMA 16x16x32 bf16 ----
    // 16 waves: wave w -> row-tile rt = w>>1 (rows e=rt*16..+15),
    // col-half ch2 = w&1 -> col-tiles cti=0..3 (co = (ch2*4+cti)*16..+15).
    {
        const int wv = tid >> 6, l = tid & 63;
        const int rt = wv >> 1, ch2 = wv & 1;
        const int r  = rt * 16 + (l & 15);           // Eq row (edge)
        const int q  = l >> 4;                       // k-subgroup 0..3
        const unsigned int* thw = (const unsigned int*)si + (ch2 ? L_TH : 0);
        const int lco = (l & 15);                    // col within tile
        f32x4v acc[4];
        #pragma unroll
        for (int i = 0; i < 4; ++i) acc[i] = (f32x4v){0.f, 0.f, 0.f, 0.f};

        #pragma unroll
        for (int kk = 0; kk < 4; ++kk) {
            // A-frag: row r, ci = kk*32 + q*8 + (0..7) -> words kk*16+q*4+(0..3), swizzled
            int aw = r * 64 + ((kk * 16 + q * 4) ^ ((r & 7) << 2));
            bf16x8v av = *(const bf16x8v*)(s_eq16 + aw);
            #pragma unroll
            for (int cti = 0; cti < 4; ++cti) {
                // B-frag: co = region-local (cti*16+lco), same k-words, swizzled by co&7
                int bw = (cti * 16 + lco) * 64 + ((kk * 16 + q * 4) ^ ((lco & 7) << 2));
                bf16x8v bv = *(const bf16x8v*)(thw + bw);
                acc[cti] = __builtin_amdgcn_mfma_f32_16x16x32_bf16(av, bv, acc[cti], 0, 0, 0);
            }
        }
        __syncthreads();         // ALL waves done reading Eq16 before Xq overlay writes

        #pragma unroll
        for (int cti = 0; cti < 4; ++cti) {
            const int co = (ch2 * 4 + cti) * 16 + lco;
            #pragma unroll
            for (int reg = 0; reg < 4; ++reg) {
                const int e = rt * 16 + q * 4 + reg;  // D row = (lane>>4)*4 + reg
                s_xq[e * XQ_STRIDE + co] = acc[cti][reg];
            }
        }
        __syncthreads();
    }

    // ---- P6: edge->node gather, D^-1 scale, bias, coalesced store ----
    {
        const int lw = tid & 31;
        const int g  = tid >> 5;             // 0..31
        float bs0 = bias[lw], bs1 = bias[lw + 32], bs2 = bias[lw + 64], bs3 = bias[lw + 96];
        for (int nn = g; nn < N_; nn += 32) {
            int o0 = s_ofn[nn], o1 = s_ofn[nn + 1];
            float f0 = 0.f, f1 = 0.f, f2 = 0.f, f3 = 0.f;
            for (int k = o0; k < o1; ++k) {
                int e = s_srt[k];
                const float* xr = s_xq + e * XQ_STRIDE;
                f0 += xr[lw];
                f1 += xr[lw + 32];
                f2 += xr[lw + 64];
                f3 += xr[lw + 96];
            }
            float dinv = (o1 > o0) ? 1.0f / (float)(o1 - o0) : 0.0f;
            size_t ob = ((size_t)bt * N_ + nn) * COUT;
            out[ob + lw     ] = f0 * dinv + bs0;
            out[ob + lw + 32] = f1 * dinv + bs1;
            out[ob + lw + 64] = f2 * dinv + bs2;
            out[ob + lw + 96] = f3 * dinv + bs3;
        }
    }
}

} // namespace

extern "C" void kernel_launch(void* const* d_in, const int* in_sizes, int n_in,
                              void* d_out, int out_size, void* d_ws, size_t ws_size,
                              hipStream_t stream) {
    const float* x     = (const float*)d_in[0];
    const int*   H     = (const int*)d_in[1];
    const float* ssa   = (const float*)d_in[2];
    // d_in[3] = W, unused by the conv (matches reference)
    const float* theta = (const float*)d_in[4];
    const float* bias  = (const float*)d_in[5];
    float* outp = (float*)d_out;

    (void)hipFuncSetAttribute((const void*)&hgconv,
                              hipFuncAttributeMaxDynamicSharedMemorySize, LDS_BYTES);

    hipLaunchKernelGGL(hgconv, dim3(B_ * T_), dim3(THREADS), LDS_BYTES, stream,
                       x, H, ssa, theta, bias, outp);
}

// Round 6
// 91.947 us; speedup vs baseline: 13.0287x; 1.1709x over previous
//
#include <hip/hip_runtime.h>
#include <cstdint>
#include <cstddef>

namespace {

constexpr int B_ = 32, F_ = 64, T_ = 20, N_ = 512, A_ = 64;
constexpr int EINC = 2048, NEDGE = 128, COUT = 128, CIN = 128;
constexpr int THREADS = 1024;

// ---- LDS layout (word offsets), total 78368 B -> 2 blocks/CU ----
// U region lifetimes: [P0..P3] s_nid/s_eid | [P4..P5a] Eq16 (8192 w)
//                     | [P5b..P6] Xq f32 (128 x 66 = 8448 w, spills into s_st)
constexpr int L_SRT  = 0;        // 2048 int  edge ids sorted by node
constexpr int L_ESRT = 2048;     // 2048 int  node ids sorted by edge
constexpr int L_OFFN = 4096;     // 513 int (+3 pad)
constexpr int L_OFFE = 4612;     // 129 int (+3 pad)
constexpr int L_DEGN = 4744;     // 512 int
constexpr int L_DEGE = 5256;     // 128 int
constexpr int L_CURN = 5384;     // 512 int
constexpr int L_CURE = 5896;     // 128 int
constexpr int L_U    = 6024;     // union region (16B aligned)
constexpr int L_ST   = 14472;    // 512*10 u32: feat chunk, packed bf16 pairs
constexpr int LDS_WORDS = 19592;
constexpr int LDS_BYTES = LDS_WORDS * 4;   // 78368
constexpr int XQ_STRIDE = 66;    // f32 words per 64-col half row (+2 pad)

typedef float f32x8 __attribute__((ext_vector_type(8)));
typedef float f32x4v __attribute__((ext_vector_type(4)));
typedef short bf16x8v __attribute__((ext_vector_type(8)));

__device__ inline unsigned short f2bf(float f) {
    unsigned int u = __float_as_uint(f);
    u = u + 0x7FFFu + ((u >> 16) & 1u);   // RNE
    return (unsigned short)(u >> 16);
}
__device__ inline unsigned packbf(float lo, float hi) {
    return ((unsigned)f2bf(hi) << 16) | (unsigned)f2bf(lo);
}

// chunk c<4: x channels (feat[n][ch] = x[b][ch][t][n], coalesced along n)
// chunk c>=4: ssa channels (float4 x2 per thread)
#define LOAD_CHUNK(CC, DST) do {                                              \
    const int c_ = (CC);                                                      \
    if (c_ < 4) {                                                             \
        const float* xr_ = x + (((size_t)b * F_ + (c_ * 16 + hf * 8)) * T_ + t) * N_ + n; \
        _Pragma("unroll")                                                     \
        for (int j_ = 0; j_ < 8; ++j_)                                        \
            DST[j_] = xr_[(size_t)j_ * T_ * N_];                              \
    } else {                                                                  \
        const float* sr_ = ssa + ((size_t)bt * N_ + n) * A_ + (c_ - 4) * 16 + hf * 8; \
        float4 u0_ = *(const float4*)(sr_);                                   \
        float4 u1_ = *(const float4*)(sr_ + 4);                               \
        DST[0] = u0_.x; DST[1] = u0_.y; DST[2] = u0_.z; DST[3] = u0_.w;       \
        DST[4] = u1_.x; DST[5] = u1_.y; DST[6] = u1_.z; DST[7] = u1_.w;       \
    }                                                                         \
} while (0)

// P6 half-pass: gather 2 f32 cols/thread from Xq over each node's edge list
#define P6PASS(P) do {                                                        \
    const int lw_ = tid & 31;                                                 \
    const int g_  = tid >> 5;                                                 \
    float2 bsv_ = *(const float2*)(bias + (P) * 64 + 2 * lw_);                \
    for (int nn_ = g_; nn_ < N_; nn_ += 32) {                                 \
        int o0_ = s_ofn[nn_], o1_ = s_ofn[nn_ + 1];                           \
        float f0_ = 0.f, f1_ = 0.f;                                           \
        for (int k_ = o0_; k_ < o1_; ++k_) {                                  \
            int e_ = s_srt[k_];                                               \
            float2 xv_ = *(const float2*)(s_xq + e_ * XQ_STRIDE + 2 * lw_);   \
            f0_ += xv_.x; f1_ += xv_.y;                                       \
        }                                                                     \
        float dinv_ = (o1_ > o0_) ? 1.0f / (float)(o1_ - o0_) : 0.0f;         \
        size_t ob_ = ((size_t)bt * N_ + nn_) * COUT + (P) * 64 + 2 * lw_;     \
        *(float2*)(out + ob_) = make_float2(f0_ * dinv_ + bsv_.x,             \
                                            f1_ * dinv_ + bsv_.y);            \
    }                                                                         \
} while (0)

// Pre-kernel: pack theta f32 -> bf16 pairs in MFMA B-frag order into d_ws.
// word w: frag f=w>>8 (=(ch2*4+cti)*4+kk), lane l=(w&255)>>2, kq=w&3;
// lane l holds co=ch2*64+cti*16+(l&15), ci=kk*32+(l>>4)*8+kq*2 (+1).
__global__ __launch_bounds__(256)
void theta_pack(const float* __restrict__ theta, unsigned* __restrict__ ws) {
    int w = blockIdx.x * 256 + threadIdx.x;     // 0..8191
    int f = w >> 8, rem = w & 255;
    int l = rem >> 2, kq = rem & 3;
    int kk = f & 3, cti = (f >> 2) & 3, ch2 = f >> 4;
    int co = ch2 * 64 + cti * 16 + (l & 15);
    int ci = kk * 32 + (l >> 4) * 8 + kq * 2;
    const float2 tv = *(const float2*)(theta + (size_t)co * CIN + ci);
    ws[w] = packbf(tv.x, tv.y);
}

__global__ __launch_bounds__(THREADS, 8)   // 8 waves/EU -> 2 blocks/CU, VGPR<=64
void hgconv(const float* __restrict__ x, const int* __restrict__ H,
            const float* __restrict__ ssa, const float* __restrict__ theta,
            const float* __restrict__ bias, float* __restrict__ out,
            const unsigned* __restrict__ thw)
{
    extern __shared__ float sf[];
    int* si = (int*)sf;

    const int tid = (int)threadIdx.x;
    const int bt  = (int)blockIdx.x;
    const int b   = bt / T_;
    const int t   = bt - b * T_;

    int* s_srt = si + L_SRT;
    int* s_esr = si + L_ESRT;
    int* s_ofn = si + L_OFFN;
    int* s_ofe = si + L_OFFE;
    int* s_dgn = si + L_DEGN;
    int* s_dge = si + L_DEGE;
    int* s_cun = si + L_CURN;
    int* s_cue = si + L_CURE;
    int* s_nid = si + L_U;                                // dead after P3
    int* s_eid = si + L_U + EINC;                         // dead after P3
    unsigned* s_eq16 = (unsigned*)si + L_U;               // P4..P5a
    float* s_xq = sf + L_U;                               // P5b..P6
    unsigned* s_st16 = (unsigned*)si + L_ST;              // feat chunk (bf16 pairs)

    const int n  = tid & (N_ - 1);
    const int hf = tid >> 9;

    // ---- P0: load incidence, zero degrees ----
    const int* Hb = H + (size_t)bt * (2 * EINC);
    #pragma unroll
    for (int k = 0; k < EINC / THREADS; ++k) {
        int i = tid + k * THREADS;
        s_nid[i] = Hb[i];
        s_eid[i] = Hb[EINC + i];
    }
    if (tid < N_)    s_dgn[tid] = 0;
    if (tid < NEDGE) s_dge[tid] = 0;
    __syncthreads();

    // ---- P1: degrees (no-return int LDS atomics) ----
    #pragma unroll
    for (int k = 0; k < EINC / THREADS; ++k) {
        int i = tid + k * THREADS;
        atomicAdd(&s_dgn[s_nid[i]], 1);
        atomicAdd(&s_dge[s_eid[i]], 1);
    }
    __syncthreads();

    // active-node predicate; issue chunk-0 load now (hides under scans/sort)
    const bool act = s_dgn[n] > 0;
    f32x8 vv;
    if (act) LOAD_CHUNK(0, vv);

    // ---- P2: exclusive scans (wave0: edges, wave1: nodes) ----
    if (tid < 64) {
        const int l = tid;
        int d0 = s_dge[2 * l], d1 = s_dge[2 * l + 1];
        int run = d0 + d1;
        int scan = run;
        #pragma unroll
        for (int d = 1; d < 64; d <<= 1) {
            int o = __shfl_up(scan, d);
            if (l >= d) scan += o;
        }
        int excl = scan - run;
        s_ofe[2 * l] = excl;
        s_ofe[2 * l + 1] = excl + d0;
        if (l == 63) s_ofe[NEDGE] = scan;
    } else if (tid < 128) {
        const int l = tid & 63;
        int v, loc[8], run = 0;
        #pragma unroll
        for (int q = 0; q < 8; ++q) { v = s_dgn[l * 8 + q]; loc[q] = run; run += v; }
        int scan = run;
        #pragma unroll
        for (int d = 1; d < 64; d <<= 1) {
            int o = __shfl_up(scan, d);
            if (l >= d) scan += o;
        }
        int excl = scan - run;
        #pragma unroll
        for (int q = 0; q < 8; ++q) s_ofn[l * 8 + q] = excl + loc[q];
        if (l == 63) s_ofn[N_] = scan;
    }
    __syncthreads();

    if (tid < N_)    s_cun[tid] = s_ofn[tid];
    if (tid < NEDGE) s_cue[tid] = s_ofe[tid];
    __syncthreads();

    // ---- P3: counting-sort scatter, both keys ----
    #pragma unroll
    for (int k = 0; k < EINC / THREADS; ++k) {
        int i = tid + k * THREADS;
        int nd = s_nid[i];
        int e  = s_eid[i];
        int pe = atomicAdd(&s_cue[e], 1);
        s_esr[pe] = nd;
        int pn = atomicAdd(&s_cun[nd], 1);
        s_srt[pn] = e;
    }
    __syncthreads();                     // s_nid/s_eid DEAD; Eq16 may now be written

    // ---- P4: per-chunk bf16 stage + edge-side gather -> Eq16 ----
    const int eg = tid >> 3;             // edge 0..127
    const int ep = tid & 7;              // channel pair 0..7
    for (int c = 0; c < 8; ++c) {
        if (act) {
            unsigned w0 = packbf(vv[0], vv[1]), w1 = packbf(vv[2], vv[3]);
            unsigned w2 = packbf(vv[4], vv[5]), w3 = packbf(vv[6], vv[7]);
            unsigned* sp = s_st16 + n * 10 + hf * 4;
            *(uint2*)(sp)     = make_uint2(w0, w1);
            *(uint2*)(sp + 2) = make_uint2(w2, w3);
        }
        __syncthreads();                 // stage visible

        f32x8 nv;
        if (c < 7 && act) LOAD_CHUNK(c + 1, nv);   // prefetch under gather

        {
            int k0 = s_ofe[eg], k1 = s_ofe[eg + 1];
            float a0 = 0.f, a1 = 0.f;
            int k = k0;
            for (; k + 1 < k1; k += 2) {
                unsigned pA = s_st16[s_esr[k] * 10 + ep];
                unsigned pB = s_st16[s_esr[k + 1] * 10 + ep];
                a0 += __uint_as_float(pA << 16) + __uint_as_float(pB << 16);
                a1 += __uint_as_float(pA & 0xFFFF0000u) + __uint_as_float(pB & 0xFFFF0000u);
            }
            if (k < k1) {
                unsigned pA = s_st16[s_esr[k] * 10 + ep];
                a0 += __uint_as_float(pA << 16);
                a1 += __uint_as_float(pA & 0xFFFF0000u);
            }
            float binv = (k1 > k0) ? 1.0f / (float)(k1 - k0) : 0.0f;
            int p = c * 8 + ep;                       // word-in-row 0..63
            s_eq16[eg * 64 + (p ^ ((eg & 7) << 2))] = packbf(a0 * binv, a1 * binv);
        }
        __syncthreads();

        if (c < 7 && act) vv = nv;
    }

    // ---- P5: Xq = Eq16 . Theta^T via MFMA; P6 interleaved in two col-halves ----
    {
        const int wv = tid >> 6, l = tid & 63;
        const int rt = wv >> 1, ch2 = wv & 1;        // row-tile, col-half
        const int r  = rt * 16 + (l & 15);
        const int q  = l >> 4;
        const int lco = l & 15;

        bf16x8v av[4];
        #pragma unroll
        for (int kk = 0; kk < 4; ++kk) {
            int aw = r * 64 + ((kk * 16 + q * 4) ^ ((r & 7) << 2));
            av[kk] = *(const bf16x8v*)(s_eq16 + aw);
        }
        f32x4v acc[4];
        #pragma unroll
        for (int i = 0; i < 4; ++i) acc[i] = (f32x4v){0.f, 0.f, 0.f, 0.f};

        if (thw) {                                   // packed frags from d_ws (L2-hot)
            #pragma unroll
            for (int cti = 0; cti < 4; ++cti) {
                #pragma unroll
                for (int kk = 0; kk < 4; ++kk) {
                    int f = (ch2 * 4 + cti) * 4 + kk;
                    uint4 u = *((const uint4*)thw + f * 64 + l);
                    bf16x8v bv = *(const bf16x8v*)&u;
                    acc[cti] = __builtin_amdgcn_mfma_f32_16x16x32_bf16(av[kk], bv, acc[cti], 0, 0, 0);
                }
            }
        } else {                                     // fallback: theta f32 + cvt
            #pragma unroll
            for (int cti = 0; cti < 4; ++cti) {
                const int co = ch2 * 64 + cti * 16 + lco;
                #pragma unroll
                for (int kk = 0; kk < 4; ++kk) {
                    const float* tp = theta + (size_t)co * CIN + kk * 32 + q * 8;
                    float4 t0 = *(const float4*)tp;
                    float4 t1 = *(const float4*)(tp + 4);
                    unsigned pw[4] = { packbf(t0.x, t0.y), packbf(t0.z, t0.w),
                                       packbf(t1.x, t1.y), packbf(t1.z, t1.w) };
                    bf16x8v bv = *(const bf16x8v*)pw;
                    acc[cti] = __builtin_amdgcn_mfma_f32_16x16x32_bf16(av[kk], bv, acc[cti], 0, 0, 0);
                }
            }
        }
        __syncthreads();                 // all Eq16 reads done; Xq overlay may begin

        if (ch2 == 0) {                  // write cols 0..63
            #pragma unroll
            for (int cti = 0; cti < 4; ++cti)
                #pragma unroll
                for (int reg = 0; reg < 4; ++reg)
                    s_xq[(rt * 16 + q * 4 + reg) * XQ_STRIDE + cti * 16 + lco] = acc[cti][reg];
        }
        __syncthreads();
        P6PASS(0);
        __syncthreads();
        if (ch2 == 1) {                  // write cols 64..127 (stored at local 0..63)
            #pragma unroll
            for (int cti = 0; cti < 4; ++cti)
                #pragma unroll
                for (int reg = 0; reg < 4; ++reg)
                    s_xq[(rt * 16 + q * 4 + reg) * XQ_STRIDE + cti * 16 + lco] = acc[cti][reg];
        }
        __syncthreads();
        P6PASS(1);
    }
}

} // namespace

extern "C" void kernel_launch(void* const* d_in, const int* in_sizes, int n_in,
                              void* d_out, int out_size, void* d_ws, size_t ws_size,
                              hipStream_t stream) {
    const float* x     = (const float*)d_in[0];
    const int*   H     = (const int*)d_in[1];
    const float* ssa   = (const float*)d_in[2];
    // d_in[3] = W, unused by the conv (matches reference)
    const float* theta = (const float*)d_in[4];
    const float* bias  = (const float*)d_in[5];
    float* outp = (float*)d_out;

    const bool use_ws = (d_ws != nullptr) && (ws_size >= 32768);
    if (use_ws)
        hipLaunchKernelGGL(theta_pack, dim3(32), dim3(256), 0, stream,
                           theta, (unsigned*)d_ws);

    (void)hipFuncSetAttribute((const void*)&hgconv,
                              hipFuncAttributeMaxDynamicSharedMemorySize, LDS_BYTES);

    hipLaunchKernelGGL(hgconv, dim3(B_ * T_), dim3(THREADS), LDS_BYTES, stream,
                       x, H, ssa, theta, bias, outp,
                       use_ws ? (const unsigned*)d_ws : nullptr);
}